// Round 7
// baseline (1308.264 us; speedup 1.0000x reference)
//
#include <hip/hip_runtime.h>

#define C_NUM 1000
#define D_DIM 128
#define MOMENTUM 0.9f
#define NB 64           // blocks per quarter (1 per 4 CUs per quarter; 256 total = 1/CU)
#define QTR 4
#define ACC_STRIDE 33   // padded LDS row stride (floats) to spread banks

// ws layout (4-byte words):
//   [0]      counts[C]
//   [1024]   sums_part[QTR * NB * C_NUM * 32]  (float)  ~32.8 MB

// ---------- counts: plain LDS histogram ----------
__global__ __launch_bounds__(256) void hist_kernel(
        const int* __restrict__ labels, int n, int* __restrict__ counts) {
    __shared__ int h[C_NUM];
    for (int i = threadIdx.x; i < C_NUM; i += 256) h[i] = 0;
    __syncthreads();
    int idx = blockIdx.x * blockDim.x + threadIdx.x;
    int stride = gridDim.x * blockDim.x;
    for (int i = idx; i < n; i += stride) atomicAdd(&h[labels[i]], 1);
    __syncthreads();
    for (int i = threadIdx.x; i < C_NUM; i += 256) {
        int v = h[i];
        if (v) atomicAdd(&counts[i], v);
    }
}

__global__ void zero_counts_kernel(int* __restrict__ counts) {
    int i = blockIdx.x * blockDim.x + threadIdx.x;
    if (i < C_NUM) counts[i] = 0;
}

// ---------- main: sequential stream + LDS-atomic class accumulation ----------
__global__ __launch_bounds__(512) void stream_accum_kernel(
        const float4* __restrict__ feat4, const int* __restrict__ labels,
        int n, float* __restrict__ sums_part) {
    __shared__ float acc[C_NUM * ACC_STRIDE];    // 132 KB
    int bid = blockIdx.x;
    int quarter = bid & 3;                        // which 32-float slice of D
    int blk = bid >> 2;                           // which row chunk
    int tid = threadIdx.x;

    for (int i = tid; i < C_NUM * ACC_STRIDE; i += 512) acc[i] = 0.f;
    __syncthreads();

    int chunk = (n + NB - 1) / NB;
    int start = blk * chunk;
    int end = min(start + chunk, n);

    int qg = tid & 7;                             // float4 index within quarter
    int ro = tid >> 3;                            // row offset 0..63
    int qbase = quarter * 8;

    int base = start;
    // main loop: 128 rows per iteration, 2 independent load batches
    for (; base + 128 <= end; base += 128) {
        int row0 = base + ro;
        int row1 = base + 64 + ro;
        int lab0 = labels[row0];
        int lab1 = labels[row1];
        float4 v0 = feat4[(long)row0 * 32 + qbase + qg];
        float4 v1 = feat4[(long)row1 * 32 + qbase + qg];
        int b0 = lab0 * ACC_STRIDE + qg * 4;
        int b1 = lab1 * ACC_STRIDE + qg * 4;
        atomicAdd(&acc[b0 + 0], v0.x);
        atomicAdd(&acc[b0 + 1], v0.y);
        atomicAdd(&acc[b0 + 2], v0.z);
        atomicAdd(&acc[b0 + 3], v0.w);
        atomicAdd(&acc[b1 + 0], v1.x);
        atomicAdd(&acc[b1 + 1], v1.y);
        atomicAdd(&acc[b1 + 2], v1.z);
        atomicAdd(&acc[b1 + 3], v1.w);
    }
    // tail: 64-row batches with guard
    for (; base < end; base += 64) {
        int row = base + ro;
        if (row < end) {
            int lab = labels[row];
            float4 v = feat4[(long)row * 32 + qbase + qg];
            int b = lab * ACC_STRIDE + qg * 4;
            atomicAdd(&acc[b + 0], v.x);
            atomicAdd(&acc[b + 1], v.y);
            atomicAdd(&acc[b + 2], v.z);
            atomicAdd(&acc[b + 3], v.w);
        }
    }
    __syncthreads();

    // dump partial: [quarter][blk][c][32], coalesced stores
    float* dst = sums_part + ((long)(quarter * NB + blk) * C_NUM) * 32;
    for (int e = tid; e < C_NUM * 32; e += 512) {
        int c = e >> 5, w = e & 31;
        dst[e] = acc[c * ACC_STRIDE + w];
    }
}

// ---------- finalize: reduce NB partials per quarter + EMA epilogue ----------
__global__ __launch_bounds__(128) void finalize_q_kernel(
        const float* __restrict__ prototypes, const float* __restrict__ sums_part,
        const int* __restrict__ counts, float* __restrict__ out) {
    __shared__ float red[D_DIM];
    int c = blockIdx.x, d = threadIdx.x;
    int quarter = d >> 5, w = d & 31;
    float s = 0.f;
    #pragma unroll 4
    for (int blk = 0; blk < NB; ++blk)
        s += sums_part[((long)(quarter * NB + blk) * C_NUM + c) * 32 + w];
    float proto = prototypes[c * D_DIM + d];
    red[d] = proto;
    __syncthreads();
    for (int t = 64; t > 0; t >>= 1) {
        if (d < t) red[d] += red[d + t];
        __syncthreads();
    }
    float rowsum = red[0];
    int cnt = counts[c];
    float mean = s / (float)max(cnt, 1);
    float ema = MOMENTUM * proto + (1.f - MOMENTUM) * mean;
    out[c * D_DIM + d] = (cnt > 0) ? ((rowsum == 0.f) ? mean : ema) : proto;
}

// ===================== fallback (atomic path, small ws) =====================
__global__ void zero_ws_words_kernel(int* __restrict__ ws, int n) {
    int i = blockIdx.x * blockDim.x + threadIdx.x;
    if (i < n) ws[i] = 0;
}

__global__ void scatter_kernel(const float4* __restrict__ feat4,
                               const int* __restrict__ labels,
                               float* __restrict__ sums, long total4) {
    long idx = (long)blockIdx.x * blockDim.x + threadIdx.x;
    long stride = (long)gridDim.x * blockDim.x;
    for (long i = idx; i < total4; i += stride) {
        float4 v = feat4[i];
        int row = (int)(i >> 5);
        int q = (int)(i & 31);
        int lab = labels[row];
        float* dst = sums + lab * D_DIM + q * 4;
        atomicAdd(dst + 0, v.x);
        atomicAdd(dst + 1, v.y);
        atomicAdd(dst + 2, v.z);
        atomicAdd(dst + 3, v.w);
    }
}

__global__ void finalize_kernel(const float* __restrict__ prototypes,
                                const float* __restrict__ sums,
                                const int* __restrict__ counts,
                                float* __restrict__ out) {
    __shared__ float red[D_DIM];
    int c = blockIdx.x;
    int d = threadIdx.x;
    float proto = prototypes[c * D_DIM + d];
    red[d] = proto;
    __syncthreads();
    for (int s = 64; s > 0; s >>= 1) {
        if (d < s) red[d] += red[d + s];
        __syncthreads();
    }
    float rowsum = red[0];
    int cnt = counts[c];
    float mean = sums[c * D_DIM + d] / (float)max(cnt, 1);
    float ema = MOMENTUM * proto + (1.0f - MOMENTUM) * mean;
    out[c * D_DIM + d] = (cnt > 0) ? ((rowsum == 0.0f) ? mean : ema) : proto;
}

// =========================================================================
extern "C" void kernel_launch(void* const* d_in, const int* in_sizes, int n_in,
                              void* d_out, int out_size, void* d_ws, size_t ws_size,
                              hipStream_t stream) {
    const float* features   = (const float*)d_in[0];
    const int*   labels     = (const int*)d_in[1];
    const float* prototypes = (const float*)d_in[2];
    float* out = (float*)d_out;
    int n = in_sizes[1];

    int* counts      = (int*)d_ws;
    float* sums_part = (float*)((int*)d_ws + 1024);

    size_t need = (size_t)1024 * 4 +
                  (size_t)QTR * NB * C_NUM * 32 * sizeof(float);
    if (ws_size >= need) {
        zero_counts_kernel<<<(C_NUM + 255) / 256, 256, 0, stream>>>(counts);
        hist_kernel<<<256, 256, 0, stream>>>(labels, n, counts);
        stream_accum_kernel<<<QTR * NB, 512, 0, stream>>>(
            (const float4*)features, labels, n, sums_part);
        finalize_q_kernel<<<C_NUM, D_DIM, 0, stream>>>(
            prototypes, sums_part, counts, out);
    } else {
        float* fsums = (float*)d_ws;
        int* fcounts = (int*)(fsums + C_NUM * D_DIM);
        int zero_n = C_NUM * D_DIM + C_NUM;
        zero_ws_words_kernel<<<(zero_n + 255) / 256, 256, 0, stream>>>((int*)d_ws, zero_n);
        hist_kernel<<<256, 256, 0, stream>>>(labels, n, fcounts);
        long total4 = (long)n * (D_DIM / 4);
        scatter_kernel<<<2048, 256, 0, stream>>>((const float4*)features, labels, fsums, total4);
        finalize_kernel<<<C_NUM, D_DIM, 0, stream>>>(prototypes, fsums, fcounts, out);
    }
}

// Round 8
// 255.732 us; speedup vs baseline: 5.1158x; 5.1158x over previous
//
#include <hip/hip_runtime.h>

#define C_NUM 1000
#define D_DIM 128
#define MOMENTUM 0.9f
#define KCHUNKS 8       // blocks per class in the partial reduce
#define NBLK 256        // partition chunks over N
#define STAGE_MAX 7936  // max chunk size the LDS-staged place supports

// ws layout (4-byte words):
//   [0]                  counts[C]
//   [C]                  offs[C+1]      (exclusive offsets + sentinel offs[C]=N)
//   [2C+1]               cursor[C]      (fallback path only)
//   [3C+1]               mat[C * NBLK]  per-(class,chunk) counts -> excl. prefix
//   [3C+1 + C*NBLK]      sums_part[K * C * D] (float)
//   [... + K*C*D]        order[N]

// ---------- phase 1: per-chunk class histogram ----------
__global__ __launch_bounds__(256) void chunk_hist_kernel(
        const int* __restrict__ labels, int n, int* __restrict__ mat) {
    __shared__ int h[C_NUM];
    int b = blockIdx.x;
    int chunk = (n + NBLK - 1) / NBLK;
    int start = b * chunk, end = min(start + chunk, n);
    for (int i = threadIdx.x; i < C_NUM; i += 256) h[i] = 0;
    __syncthreads();
    for (int i = start + threadIdx.x; i < end; i += 256)
        atomicAdd(&h[labels[i]], 1);
    __syncthreads();
    for (int c = threadIdx.x; c < C_NUM; c += 256)
        mat[c * NBLK + b] = h[c];
}

// ---------- phase 2: per-class exclusive scan over chunks ----------
__global__ __launch_bounds__(256) void scan_mat_kernel(
        int* __restrict__ mat, int* __restrict__ counts) {
    __shared__ int s[NBLK];
    int c = blockIdx.x;
    int t = threadIdx.x;
    int* row = mat + c * NBLK;
    int v = row[t];
    s[t] = v;
    __syncthreads();
    for (int d = 1; d < NBLK; d <<= 1) {
        int val = (t >= d) ? s[t - d] : 0;
        __syncthreads();
        s[t] += val;
        __syncthreads();
    }
    row[t] = s[t] - v;              // exclusive
    if (t == NBLK - 1) counts[c] = s[NBLK - 1];
}

// ---------- phase 2b: class-level exclusive offsets (+ sentinel) ----------
__global__ void scan_offsets_kernel(const int* __restrict__ counts,
                                    int* __restrict__ offs) {
    __shared__ int s[1024];
    int t = threadIdx.x;
    int c = (t < C_NUM) ? counts[t] : 0;
    s[t] = c;
    __syncthreads();
    for (int d = 1; d < 1024; d <<= 1) {
        int v = (t >= d) ? s[t - d] : 0;
        __syncthreads();
        s[t] += v;
        __syncthreads();
    }
    if (t < C_NUM) offs[t] = s[t] - c;           // exclusive
    if (t == C_NUM - 1) offs[C_NUM] = s[t];      // sentinel = N
}

// ---------- phase 3: LDS-staged place -> class-contiguous burst writes ----------
__global__ __launch_bounds__(256) void place_staged_kernel(
        const int* __restrict__ labels, int n,
        const int* __restrict__ mat, const int* __restrict__ offs,
        int* __restrict__ order) {
    __shared__ int h[1024];         // hist, later reused as cursor
    __shared__ int loc[1028];       // exclusive local offsets
    __shared__ int gbase[C_NUM];    // global dest base per class for this chunk
    __shared__ int ps[256];
    __shared__ int stage[STAGE_MAX];
    int b = blockIdx.x;
    int t = threadIdx.x;
    int chunk = (n + NBLK - 1) / NBLK;
    int start = b * chunk, end = min(start + chunk, n);
    int m = end - start;

    for (int i = t; i < 1024; i += 256) h[i] = 0;
    for (int c = t; c < C_NUM; c += 256)
        gbase[c] = offs[c] + mat[c * NBLK + b];
    __syncthreads();
    for (int i = start + t; i < end; i += 256)
        atomicAdd(&h[labels[i]], 1);
    __syncthreads();

    // exclusive scan of h[0..1023] -> loc, 4 classes per thread
    int c4 = t * 4;
    int a0 = h[c4], a1 = h[c4 + 1], a2 = h[c4 + 2], a3 = h[c4 + 3];
    int ssum = a0 + a1 + a2 + a3;
    ps[t] = ssum;
    __syncthreads();
    for (int d = 1; d < 256; d <<= 1) {
        int v = (t >= d) ? ps[t - d] : 0;
        __syncthreads();
        ps[t] += v;
        __syncthreads();
    }
    int excl = ps[t] - ssum;
    loc[c4]     = excl;
    loc[c4 + 1] = excl + a0;
    loc[c4 + 2] = excl + a0 + a1;
    loc[c4 + 3] = excl + a0 + a1 + a2;
    __syncthreads();

    // reuse h as local cursor
    for (int c = t; c < C_NUM; c += 256) h[c] = loc[c];
    __syncthreads();

    // stage indices into class-sorted local positions
    for (int i = start + t; i < end; i += 256) {
        int lab = labels[i];
        int p = atomicAdd(&h[lab], 1);
        stage[p] = i;
    }
    __syncthreads();

    // write out: consecutive local j within a class run -> consecutive global dest
    for (int j = t; j < m; j += 256) {
        int lo = 0, hi = C_NUM - 1;                // largest c with loc[c] <= j
        while (lo < hi) {
            int mid = (lo + hi + 1) >> 1;
            if (loc[mid] <= j) lo = mid; else hi = mid - 1;
        }
        order[gbase[lo] + (j - loc[lo])] = stage[j];
    }
}

// ---------- fallback place (global atomics) for oversized chunks ----------
__global__ void init_cursor_kernel(const int* __restrict__ offs,
                                   int* __restrict__ cursor) {
    int i = blockIdx.x * blockDim.x + threadIdx.x;
    if (i < C_NUM) cursor[i] = offs[i];
}

__global__ void build_order_kernel(const int* __restrict__ labels, int n,
                                   int* __restrict__ cursor,
                                   int* __restrict__ order) {
    int idx = blockIdx.x * blockDim.x + threadIdx.x;
    int stride = gridDim.x * blockDim.x;
    for (int i = idx; i < n; i += stride) {
        int lab = labels[i];
        int pos = atomicAdd(&cursor[lab], 1);
        order[pos] = i;
    }
}

// ---------- phase 4: gather-reduce, 8-deep pipeline ----------
__global__ __launch_bounds__(256) void partial_reduce_kernel(
        const float4* __restrict__ feat4, const int* __restrict__ order,
        const int* __restrict__ offs, float* __restrict__ sums_part) {
    int c = blockIdx.x >> 3;          // / KCHUNKS
    int k = blockIdx.x & (KCHUNKS - 1);
    int off = offs[c];
    int cend = offs[c + 1];
    int len = (cend - off + KCHUNKS - 1) / KCHUNKS;
    int start = off + k * len;
    int end = min(start + len, cend);

    int tid = threadIdx.x;
    int sub = tid >> 5;               // 0..7
    int q = tid & 31;                 // float4 lane within row

    float4 acc = make_float4(0.f, 0.f, 0.f, 0.f);
    int j = start + sub;

    // 8 rows in flight per subgroup
    for (; j + 56 < end; j += 64) {
        int r0 = order[j],      r1 = order[j + 8],  r2 = order[j + 16], r3 = order[j + 24];
        int r4 = order[j + 32], r5 = order[j + 40], r6 = order[j + 48], r7 = order[j + 56];
        float4 v0 = feat4[(long)r0 * 32 + q];
        float4 v1 = feat4[(long)r1 * 32 + q];
        float4 v2 = feat4[(long)r2 * 32 + q];
        float4 v3 = feat4[(long)r3 * 32 + q];
        float4 v4 = feat4[(long)r4 * 32 + q];
        float4 v5 = feat4[(long)r5 * 32 + q];
        float4 v6 = feat4[(long)r6 * 32 + q];
        float4 v7 = feat4[(long)r7 * 32 + q];
        acc.x += ((v0.x + v1.x) + (v2.x + v3.x)) + ((v4.x + v5.x) + (v6.x + v7.x));
        acc.y += ((v0.y + v1.y) + (v2.y + v3.y)) + ((v4.y + v5.y) + (v6.y + v7.y));
        acc.z += ((v0.z + v1.z) + (v2.z + v3.z)) + ((v4.z + v5.z) + (v6.z + v7.z));
        acc.w += ((v0.w + v1.w) + (v2.w + v3.w)) + ((v4.w + v5.w) + (v6.w + v7.w));
    }
    // 4-deep
    for (; j + 24 < end; j += 32) {
        int r0 = order[j], r1 = order[j + 8], r2 = order[j + 16], r3 = order[j + 24];
        float4 v0 = feat4[(long)r0 * 32 + q];
        float4 v1 = feat4[(long)r1 * 32 + q];
        float4 v2 = feat4[(long)r2 * 32 + q];
        float4 v3 = feat4[(long)r3 * 32 + q];
        acc.x += (v0.x + v1.x) + (v2.x + v3.x);
        acc.y += (v0.y + v1.y) + (v2.y + v3.y);
        acc.z += (v0.z + v1.z) + (v2.z + v3.z);
        acc.w += (v0.w + v1.w) + (v2.w + v3.w);
    }
    // tail
    for (; j < end; j += 8) {
        int r = order[j];
        float4 v = feat4[(long)r * 32 + q];
        acc.x += v.x; acc.y += v.y; acc.z += v.z; acc.w += v.w;
    }

    __shared__ float4 lds4[256];
    lds4[tid] = acc;
    __syncthreads();
    if (tid < D_DIM) {
        const float* lds = (const float*)lds4;
        float s = 0.f;
        #pragma unroll
        for (int g = 0; g < 8; ++g) s += lds[g * D_DIM + tid];
        sums_part[((long)k * C_NUM + c) * D_DIM + tid] = s;  // plain store
    }
}

// ---------- phase 5: reduce slices + EMA epilogue ----------
__global__ __launch_bounds__(128) void finalize_slices_kernel(
        const float* __restrict__ prototypes, const float* __restrict__ sums_part,
        const int* __restrict__ counts, float* __restrict__ out) {
    __shared__ float red[D_DIM];
    int c = blockIdx.x, d = threadIdx.x;
    float s = 0.f;
    #pragma unroll
    for (int k = 0; k < KCHUNKS; ++k)
        s += sums_part[((long)k * C_NUM + c) * D_DIM + d];
    float proto = prototypes[c * D_DIM + d];
    red[d] = proto;
    __syncthreads();
    for (int t = 64; t > 0; t >>= 1) {
        if (d < t) red[d] += red[d + t];
        __syncthreads();
    }
    float rowsum = red[0];
    int cnt = counts[c];
    float mean = s / (float)max(cnt, 1);
    float ema = MOMENTUM * proto + (1.f - MOMENTUM) * mean;
    out[c * D_DIM + d] = (cnt > 0) ? ((rowsum == 0.f) ? mean : ema) : proto;
}

// ===================== fallback (atomic path, small ws) =====================
__global__ void zero_ws_words_kernel(int* __restrict__ ws, int n) {
    int i = blockIdx.x * blockDim.x + threadIdx.x;
    if (i < n) ws[i] = 0;
}

__global__ void hist_kernel(const int* __restrict__ labels, int n,
                            int* __restrict__ counts) {
    __shared__ int h[C_NUM];
    for (int i = threadIdx.x; i < C_NUM; i += blockDim.x) h[i] = 0;
    __syncthreads();
    int idx = blockIdx.x * blockDim.x + threadIdx.x;
    int stride = gridDim.x * blockDim.x;
    for (int i = idx; i < n; i += stride) atomicAdd(&h[labels[i]], 1);
    __syncthreads();
    for (int i = threadIdx.x; i < C_NUM; i += blockDim.x) {
        int v = h[i];
        if (v) atomicAdd(&counts[i], v);
    }
}

__global__ void scatter_kernel(const float4* __restrict__ feat4,
                               const int* __restrict__ labels,
                               float* __restrict__ sums, long total4) {
    long idx = (long)blockIdx.x * blockDim.x + threadIdx.x;
    long stride = (long)gridDim.x * blockDim.x;
    for (long i = idx; i < total4; i += stride) {
        float4 v = feat4[i];
        int row = (int)(i >> 5);
        int q = (int)(i & 31);
        int lab = labels[row];
        float* dst = sums + lab * D_DIM + q * 4;
        atomicAdd(dst + 0, v.x);
        atomicAdd(dst + 1, v.y);
        atomicAdd(dst + 2, v.z);
        atomicAdd(dst + 3, v.w);
    }
}

__global__ void finalize_kernel(const float* __restrict__ prototypes,
                                const float* __restrict__ sums,
                                const int* __restrict__ counts,
                                float* __restrict__ out) {
    __shared__ float red[D_DIM];
    int c = blockIdx.x;
    int d = threadIdx.x;
    float proto = prototypes[c * D_DIM + d];
    red[d] = proto;
    __syncthreads();
    for (int s = 64; s > 0; s >>= 1) {
        if (d < s) red[d] += red[d + s];
        __syncthreads();
    }
    float rowsum = red[0];
    int cnt = counts[c];
    float mean = sums[c * D_DIM + d] / (float)max(cnt, 1);
    float ema = MOMENTUM * proto + (1.0f - MOMENTUM) * mean;
    out[c * D_DIM + d] = (cnt > 0) ? ((rowsum == 0.0f) ? mean : ema) : proto;
}

// =========================================================================
extern "C" void kernel_launch(void* const* d_in, const int* in_sizes, int n_in,
                              void* d_out, int out_size, void* d_ws, size_t ws_size,
                              hipStream_t stream) {
    const float* features   = (const float*)d_in[0];
    const int*   labels     = (const int*)d_in[1];
    const float* prototypes = (const float*)d_in[2];
    float* out = (float*)d_out;
    int n = in_sizes[1];

    int* counts      = (int*)d_ws;
    int* offs        = counts + C_NUM;            // C+1 entries (sentinel)
    int* cursor      = offs + C_NUM + 1;
    int* mat         = cursor + C_NUM;
    float* sums_part = (float*)(mat + (size_t)C_NUM * NBLK);
    int* order       = (int*)(sums_part + (size_t)KCHUNKS * C_NUM * D_DIM);

    size_t need = ((size_t)3 * C_NUM + 1 + (size_t)C_NUM * NBLK +
                   (size_t)KCHUNKS * C_NUM * D_DIM + (size_t)n) * sizeof(int);
    if (ws_size >= need) {
        int chunk = (n + NBLK - 1) / NBLK;
        chunk_hist_kernel<<<NBLK, 256, 0, stream>>>(labels, n, mat);
        scan_mat_kernel<<<C_NUM, NBLK, 0, stream>>>(mat, counts);
        scan_offsets_kernel<<<1, 1024, 0, stream>>>(counts, offs);
        if (chunk <= STAGE_MAX) {
            place_staged_kernel<<<NBLK, 256, 0, stream>>>(labels, n, mat, offs, order);
        } else {
            init_cursor_kernel<<<(C_NUM + 255) / 256, 256, 0, stream>>>(offs, cursor);
            build_order_kernel<<<1024, 256, 0, stream>>>(labels, n, cursor, order);
        }
        partial_reduce_kernel<<<C_NUM * KCHUNKS, 256, 0, stream>>>(
            (const float4*)features, order, offs, sums_part);
        finalize_slices_kernel<<<C_NUM, D_DIM, 0, stream>>>(
            prototypes, sums_part, counts, out);
    } else {
        float* fsums = (float*)d_ws;
        int* fcounts = (int*)(fsums + C_NUM * D_DIM);
        int zero_n = C_NUM * D_DIM + C_NUM;
        zero_ws_words_kernel<<<(zero_n + 255) / 256, 256, 0, stream>>>((int*)d_ws, zero_n);
        hist_kernel<<<512, 256, 0, stream>>>(labels, n, fcounts);
        long total4 = (long)n * (D_DIM / 4);
        scatter_kernel<<<2048, 256, 0, stream>>>((const float4*)features, labels, fsums, total4);
        finalize_kernel<<<C_NUM, D_DIM, 0, stream>>>(prototypes, fsums, fcounts, out);
    }
}